// Round 1
// baseline (4251.749 us; speedup 1.0000x reference)
//
#include <hip/hip_runtime.h>

#define B8 8

// ---------------------------------------------------------------------------
// conv3x3 on 16x16 spatial, zero-pad SAME, K-sliced partial sums.
// grid.x = B8 * (Cout/16) * nSlice, block = 256 (thread = pixel).
// part layout: [nSlice][B8][Cout][256]
// ---------------------------------------------------------------------------
__global__ __launch_bounds__(256) void conv3x3_partial(
    const float* __restrict__ in,   // [B8, Cin, 16, 16]
    const float* __restrict__ wgt,  // [Cout, Cin, 3, 3]
    float* __restrict__ part, int Cin, int Cout, int nSlice)
{
  int nCog = Cout >> 4;
  int t = blockIdx.x;
  int slice = t % nSlice;
  int cog = (t / nSlice) % nCog;
  int b = t / (nSlice * nCog);
  int cinPer = Cin / nSlice;
  int ci0 = slice * cinPer;

  __shared__ float sIn[4][324];  // 4 planes of 18x18 (zero halo)
  int tid = threadIdx.x;
  int px = tid & 15, py = tid >> 4;
  for (int i = tid; i < 1296; i += 256) ((float*)sIn)[i] = 0.0f;

  float acc[16];
#pragma unroll
  for (int co = 0; co < 16; ++co) acc[co] = 0.0f;

  const float* inb = in + (size_t)b * Cin * 256;
  const float* wb = wgt + (size_t)(cog * 16) * Cin * 9;
  int ldsIdx = (py + 1) * 18 + px + 1;

  for (int cg = 0; cg < cinPer; cg += 4) {
    __syncthreads();
#pragma unroll
    for (int p = 0; p < 4; ++p)
      sIn[p][ldsIdx] = inb[(size_t)(ci0 + cg + p) * 256 + tid];
    __syncthreads();
#pragma unroll
    for (int p = 0; p < 4; ++p) {
      float in9[9];
#pragma unroll
      for (int ky = 0; ky < 3; ++ky)
#pragma unroll
        for (int kx = 0; kx < 3; ++kx)
          in9[ky * 3 + kx] = sIn[p][(py + ky) * 18 + px + kx];
      int ci = ci0 + cg + p;
#pragma unroll
      for (int co = 0; co < 16; ++co) {
        const float* wp = wb + ((size_t)co * Cin + ci) * 9;  // block-uniform -> s_load
#pragma unroll
        for (int k = 0; k < 9; ++k) acc[co] = fmaf(in9[k], wp[k], acc[co]);
      }
    }
  }
  float* po = part + (((size_t)slice * B8 + b) * Cout + cog * 16) * 256 + tid;
#pragma unroll
  for (int co = 0; co < 16; ++co) po[co * 256] = acc[co];
}

// ---------------------------------------------------------------------------
// sum K-slices + BN + ReLU; optional global-average-pool broadcast write into
// channels [Cout, 2*Cout) of out (for the concat feeding cls0).
// grid.x = B8*Cout, block = 256 (thread = pixel).
// ---------------------------------------------------------------------------
__global__ __launch_bounds__(256) void combine_bn_relu(
    const float* __restrict__ part, const float* __restrict__ scale,
    const float* __restrict__ shift, float* __restrict__ out,
    int Cout, int nSlice, int outStride, int doPool)
{
  int c = blockIdx.x % Cout, b = blockIdx.x / Cout;
  int tid = threadIdx.x;
  float s = 0.0f;
  for (int sl = 0; sl < nSlice; ++sl)
    s += part[(((size_t)sl * B8 + b) * Cout + c) * 256 + tid];
  float v = fmaf(s, scale[c], shift[c]);
  v = v > 0.0f ? v : 0.0f;
  out[((size_t)b * outStride + c) * 256 + tid] = v;
  if (doPool) {
    __shared__ float red[4];
    float w = v;
#pragma unroll
    for (int off = 32; off > 0; off >>= 1) w += __shfl_down(w, off, 64);
    if ((tid & 63) == 0) red[tid >> 6] = w;
    __syncthreads();
    float m = (red[0] + red[1] + red[2] + red[3]) * (1.0f / 256.0f);
    out[((size_t)b * outStride + Cout + c) * 256 + tid] = m;
  }
}

// ---------------------------------------------------------------------------
// conv3x3 256->48 + BN + ReLU on 128x128. grid.x = B8*64*3 (3 cout groups).
// block = 256 threads = one 16x16 spatial tile.
// ---------------------------------------------------------------------------
__global__ __launch_bounds__(256) void conv3x3_hi(
    const float* __restrict__ in,   // [B8,256,128,128]
    const float* __restrict__ wgt,  // [48,256,3,3]
    const float* __restrict__ scale, const float* __restrict__ shift,
    float* __restrict__ out)        // [B8,48,128,128]
{
  int t = blockIdx.x;
  int cog = t % 3;
  int tile = (t / 3) & 63;
  int b = t / 192;
  int ty0 = (tile >> 3) << 4, tx0 = (tile & 7) << 4;
  __shared__ float sIn[4][324];
  int tid = threadIdx.x;
  int px = tid & 15, py = tid >> 4;
  float acc[16];
#pragma unroll
  for (int co = 0; co < 16; ++co) acc[co] = 0.0f;
  const float* inb = in + (size_t)b * 256 * 16384;
  const float* wb = wgt + (size_t)(cog * 16) * 256 * 9;

  for (int cg = 0; cg < 256; cg += 4) {
    __syncthreads();
    for (int i = tid; i < 1296; i += 256) {
      int p = i / 324;
      int r = i - p * 324;
      int rr = r / 18, cc = r - rr * 18;
      int gy = ty0 + rr - 1, gx = tx0 + cc - 1;
      float v = 0.0f;
      if ((unsigned)gy < 128u && (unsigned)gx < 128u)
        v = inb[(size_t)(cg + p) * 16384 + gy * 128 + gx];
      ((float*)sIn)[i] = v;
    }
    __syncthreads();
#pragma unroll
    for (int p = 0; p < 4; ++p) {
      float in9[9];
#pragma unroll
      for (int ky = 0; ky < 3; ++ky)
#pragma unroll
        for (int kx = 0; kx < 3; ++kx)
          in9[ky * 3 + kx] = sIn[p][(py + ky) * 18 + px + kx];
      int ci = cg + p;
#pragma unroll
      for (int co = 0; co < 16; ++co) {
        const float* wp = wb + ((size_t)co * 256 + ci) * 9;
#pragma unroll
        for (int k = 0; k < 9; ++k) acc[co] = fmaf(in9[k], wp[k], acc[co]);
      }
    }
  }
  int oy = ty0 + py, ox = tx0 + px;
#pragma unroll
  for (int co = 0; co < 16; ++co) {
    int c = cog * 16 + co;
    float v = fmaf(acc[co], scale[c], shift[c]);
    v = v > 0.0f ? v : 0.0f;
    out[((size_t)b * 48 + c) * 16384 + oy * 128 + ox] = v;
  }
}

// ---------------------------------------------------------------------------
// conv1x1 48->16 + bias on 128x128. grid.x = B8*64, block=256.
// ---------------------------------------------------------------------------
__global__ __launch_bounds__(256) void conv1x1_lo(
    const float* __restrict__ in,   // [B8,48,16384]
    const float* __restrict__ wgt,  // [16,48]
    const float* __restrict__ bias, // [16]
    float* __restrict__ out)        // [B8,16,16384]
{
  int b = blockIdx.x >> 6;
  int px = ((blockIdx.x & 63) << 8) + threadIdx.x;
  float acc[16];
#pragma unroll
  for (int co = 0; co < 16; ++co) acc[co] = 0.0f;
#pragma unroll 4
  for (int ci = 0; ci < 48; ++ci) {
    float xv = in[((size_t)b * 48 + ci) * 16384 + px];
#pragma unroll
    for (int co = 0; co < 16; ++co) acc[co] = fmaf(xv, wgt[co * 48 + ci], acc[co]);
  }
#pragma unroll
  for (int co = 0; co < 16; ++co)
    out[((size_t)b * 16 + co) * 16384 + px] = acc[co] + bias[co];
}

// ---------------------------------------------------------------------------
// conv1x1 1024->4928 + bias (hyper-params). grid.x = B8*154 (32 cout/block).
// ---------------------------------------------------------------------------
__global__ __launch_bounds__(256) void conv1x1_hyper(
    const float* __restrict__ x2,   // [B8,1024,256]
    const float* __restrict__ wgt,  // [4928,1024]
    const float* __restrict__ bias, // [4928]
    float* __restrict__ hyper)      // [B8,4928,256]
{
  int cog = blockIdx.x % 154, b = blockIdx.x / 154;
  int co0 = cog * 32;
  int tid = threadIdx.x;
  float acc[32];
#pragma unroll
  for (int i = 0; i < 32; ++i) acc[i] = 0.0f;
  const float* xb = x2 + (size_t)b * 1024 * 256 + tid;
#pragma unroll 4
  for (int ci = 0; ci < 1024; ++ci) {
    float xv = xb[(size_t)ci * 256];
    const float* wp = wgt + (size_t)co0 * 1024 + ci;  // uniform -> s_load
#pragma unroll
    for (int co = 0; co < 32; ++co) acc[co] = fmaf(xv, wp[(size_t)co * 1024], acc[co]);
  }
  float* hb = hyper + ((size_t)b * 4928 + co0) * 256 + tid;
#pragma unroll
  for (int co = 0; co < 32; ++co) hb[co * 256] = acc[co] + bias[co0 + co];
}

// ---------------------------------------------------------------------------
// dynamic per-pixel MLP: 18 -> 16 -> 16 -> 256 with weights nearest-upsampled
// from the 16x16 hyper grid. grid.x = B8*16*4 (b, h-row, po-quarter of 64),
// block = 256 threads: thread = (r2 = tid>>7, xf = tid&127), owns 4 rows.
// hyper channel map: w0@0 [16x18], b0@288, w1@304 [16x16], b1@560,
//                    w2@576 [256x16], b2@4672 [256].
// ---------------------------------------------------------------------------
__global__ __launch_bounds__(256) void dyn_mlp(
    const float* __restrict__ hyper,  // [B8,4928,16,16]
    const float* __restrict__ c1,     // [B8,16,128,128]
    const float* __restrict__ catS, const float* __restrict__ catB,  // [18]
    float* __restrict__ out)          // [B8,256,128,128]
{
  int t = blockIdx.x;
  int q = t & 3;
  int h = (t >> 2) & 15;
  int b = t >> 6;
  int tid = threadIdx.x;
  int xf = tid & 127, r2 = tid >> 7;
  int w = xf >> 3;

  __shared__ float smem[16 * 578];  // stage1: stride 578/w-block; later w2 chunk stride 518
  __shared__ float sB2[16 * 33];

  const float* hypb = hyper + (size_t)b * 4928 * 256 + h * 16;

  // stage w0/b0/w1/b1 for the 16 w-blocks of this h-row
  for (int i = tid; i < 576 * 16; i += 256) {
    int ch = i >> 4, ww = i & 15;
    smem[ww * 578 + ch] = hypb[(size_t)ch * 256 + ww];
  }

  float cs[18], cb[18];
#pragma unroll
  for (int i = 0; i < 18; ++i) { cs[i] = catS[i]; cb[i] = catB[i]; }

  float inpv[4][18];
  int yf0 = h * 8 + r2 * 4;
  float cx = (float)(xf & 7) * 0.125f;
#pragma unroll
  for (int k = 0; k < 4; ++k) {
    inpv[k][0] = fmaf(cx, cs[0], cb[0]);
    inpv[k][1] = fmaf((float)((yf0 + k) & 7) * 0.125f, cs[1], cb[1]);
#pragma unroll
    for (int ci = 0; ci < 16; ++ci) {
      float v = c1[((size_t)b * 16 + ci) * 16384 + (size_t)(yf0 + k) * 128 + xf];
      inpv[k][2 + ci] = fmaf(v, cs[2 + ci], cb[2 + ci]);
    }
  }
  __syncthreads();

  const float* sw = smem + w * 578;
  float h0v[4][16];
  {
    const float2* w0p = (const float2*)sw;
#pragma unroll
    for (int co = 0; co < 16; ++co) {
      float a0 = sw[288 + co], a1 = a0, a2 = a0, a3 = a0;
#pragma unroll
      for (int c2 = 0; c2 < 9; ++c2) {
        float2 wv = w0p[co * 9 + c2];
        a0 = fmaf(wv.x, inpv[0][2 * c2], a0); a0 = fmaf(wv.y, inpv[0][2 * c2 + 1], a0);
        a1 = fmaf(wv.x, inpv[1][2 * c2], a1); a1 = fmaf(wv.y, inpv[1][2 * c2 + 1], a1);
        a2 = fmaf(wv.x, inpv[2][2 * c2], a2); a2 = fmaf(wv.y, inpv[2][2 * c2 + 1], a2);
        a3 = fmaf(wv.x, inpv[3][2 * c2], a3); a3 = fmaf(wv.y, inpv[3][2 * c2 + 1], a3);
      }
      h0v[0][co] = fmaxf(a0, 0.0f); h0v[1][co] = fmaxf(a1, 0.0f);
      h0v[2][co] = fmaxf(a2, 0.0f); h0v[3][co] = fmaxf(a3, 0.0f);
    }
  }
  float h1v[4][16];
  {
    const float2* w1p = (const float2*)(sw + 304);
#pragma unroll
    for (int co = 0; co < 16; ++co) {
      float a0 = sw[560 + co], a1 = a0, a2 = a0, a3 = a0;
#pragma unroll
      for (int c2 = 0; c2 < 8; ++c2) {
        float2 wv = w1p[co * 8 + c2];
        a0 = fmaf(wv.x, h0v[0][2 * c2], a0); a0 = fmaf(wv.y, h0v[0][2 * c2 + 1], a0);
        a1 = fmaf(wv.x, h0v[1][2 * c2], a1); a1 = fmaf(wv.y, h0v[1][2 * c2 + 1], a1);
        a2 = fmaf(wv.x, h0v[2][2 * c2], a2); a2 = fmaf(wv.y, h0v[2][2 * c2 + 1], a2);
        a3 = fmaf(wv.x, h0v[3][2 * c2], a3); a3 = fmaf(wv.y, h0v[3][2 * c2 + 1], a3);
      }
      h1v[0][co] = fmaxf(a0, 0.0f); h1v[1][co] = fmaxf(a1, 0.0f);
      h1v[2][co] = fmaxf(a2, 0.0f); h1v[3][co] = fmaxf(a3, 0.0f);
    }
  }

  for (int chunk = 0; chunk < 2; ++chunk) {
    int po0 = q * 64 + chunk * 32;
    __syncthreads();  // protect smem reuse
    for (int i = tid; i < 8192; i += 256) {
      int ch = i >> 4, ww = i & 15;
      smem[ww * 518 + ch] = hypb[(size_t)(576 + po0 * 16 + ch) * 256 + ww];
    }
    for (int i = tid; i < 512; i += 256) {
      int po = i >> 4, ww = i & 15;
      sB2[ww * 33 + po] = hypb[(size_t)(4672 + po0 + po) * 256 + ww];
    }
    __syncthreads();
    const float2* w2p = (const float2*)(smem + w * 518);
    const float* sb2 = sB2 + w * 33;
#pragma unroll 4
    for (int po = 0; po < 32; ++po) {
      float a0 = sb2[po], a1 = a0, a2 = a0, a3 = a0;
#pragma unroll
      for (int c2 = 0; c2 < 8; ++c2) {
        float2 wv = w2p[po * 8 + c2];
        a0 = fmaf(wv.x, h1v[0][2 * c2], a0); a0 = fmaf(wv.y, h1v[0][2 * c2 + 1], a0);
        a1 = fmaf(wv.x, h1v[1][2 * c2], a1); a1 = fmaf(wv.y, h1v[1][2 * c2 + 1], a1);
        a2 = fmaf(wv.x, h1v[2][2 * c2], a2); a2 = fmaf(wv.y, h1v[2][2 * c2 + 1], a2);
        a3 = fmaf(wv.x, h1v[3][2 * c2], a3); a3 = fmaf(wv.y, h1v[3][2 * c2 + 1], a3);
      }
      size_t ob = ((size_t)b * 256 + po0 + po) * 16384 + (size_t)yf0 * 128 + xf;
      out[ob] = a0; out[ob + 128] = a1; out[ob + 256] = a2; out[ob + 384] = a3;
    }
  }
}

// ---------------------------------------------------------------------------
extern "C" void kernel_launch(void* const* d_in, const int* in_sizes, int n_in,
                              void* d_out, int out_size, void* d_ws, size_t ws_size,
                              hipStream_t stream) {
  const float* res5 = (const float*)d_in[0];
  const float* res2 = (const float*)d_in[1];
  const float* bw   = (const float*)d_in[2];
  const float* bn1s = (const float*)d_in[3];
  const float* bn1b = (const float*)d_in[4];
  const float* c0w  = (const float*)d_in[5];
  const float* bn2s = (const float*)d_in[6];
  const float* bn2b = (const float*)d_in[7];
  const float* cls1w = (const float*)d_in[8];
  const float* cls1b = (const float*)d_in[9];
  const float* c1aw = (const float*)d_in[10];
  const float* bn3s = (const float*)d_in[11];
  const float* bn3b = (const float*)d_in[12];
  const float* c1bw = (const float*)d_in[13];
  const float* c1bb = (const float*)d_in[14];
  const float* catS = (const float*)d_in[15];
  const float* catB = (const float*)d_in[16];
  float* out = (float*)d_out;
  float* ws = (float*)d_ws;

  float* partial = ws;                  // 4,194,304 floats (max of both conv partials)
  float* x2cat   = ws + 4194304;        // 2,097,152  [8,1024,16,16]
  float* x2      = ws + 6291456;        // 2,097,152  [8,1024,16,16]
  float* hyper   = ws + 8388608;        // 10,092,544 [8,4928,16,16]
  float* c1mid   = ws + 18481152;       // 6,291,456  [8,48,128,128]
  float* c1      = ws + 24772608;       // 2,097,152  [8,16,128,128]

  // bottleneck conv (2048->512), 4 K-slices
  conv3x3_partial<<<8 * 32 * 4, 256, 0, stream>>>(res5, bw, partial, 2048, 512, 4);
  combine_bn_relu<<<8 * 512, 256, 0, stream>>>(partial, bn1s, bn1b, x2cat, 512, 4, 1024, 1);
  // cls0 conv (1024->1024), 2 K-slices
  conv3x3_partial<<<8 * 64 * 2, 256, 0, stream>>>(x2cat, c0w, partial, 1024, 1024, 2);
  combine_bn_relu<<<8 * 1024, 256, 0, stream>>>(partial, bn2s, bn2b, x2, 1024, 2, 1024, 0);
  // cls1 1x1 (1024->4928)
  conv1x1_hyper<<<8 * 154, 256, 0, stream>>>(x2, cls1w, cls1b, hyper);
  // low-level branch
  conv3x3_hi<<<8 * 64 * 3, 256, 0, stream>>>(res2, c1aw, bn3s, bn3b, c1mid);
  conv1x1_lo<<<8 * 64, 256, 0, stream>>>(c1mid, c1bw, c1bb, c1);
  // dynamic MLP
  dyn_mlp<<<8 * 16 * 4, 256, 0, stream>>>(hyper, c1, catS, catB, out);
}

// Round 2
// 2047.826 us; speedup vs baseline: 2.0762x; 2.0762x over previous
//
#include <hip/hip_runtime.h>

#define B8 8

typedef __attribute__((ext_vector_type(8))) short short8;
typedef __attribute__((ext_vector_type(4))) float floatx4;

static __device__ __forceinline__ unsigned short f2bf(float f) {
  unsigned int u = __float_as_uint(f);
  unsigned int r = (u + 0x7fffu + ((u >> 16) & 1u)) >> 16;
  return (unsigned short)r;
}

// ---------------------------------------------------------------------------
// weight transform: w[co][ci][ky][kx] fp32 -> wT[tap][co][ci] bf16
// ---------------------------------------------------------------------------
__global__ __launch_bounds__(256) void wtransform(
    const float* __restrict__ w, unsigned short* __restrict__ wT,
    int Cout, int Cin)
{
  int idx = blockIdx.x * 256 + threadIdx.x;
  if (idx >= Cout * Cin) return;
  int ci = idx % Cin, co = idx / Cin;
  const float* s = w + (size_t)idx * 9;
#pragma unroll
  for (int t = 0; t < 9; ++t)
    wT[((size_t)t * Cout + co) * Cin + ci] = f2bf(s[t]);
}

// ---------------------------------------------------------------------------
// bf16 MFMA conv3x3 on 16x16 spatial, SAME zero pad, K-sliced.
// Orientation: D[m=co][n=px]. A = weights from GLOBAL (wT[tap][co][ci]),
// B = input pixels from LDS (pixel-major, ciPad=40 for aligned b128 + 2-way).
// Block: 256 thr = 4 waves (2 co-halves x 2 px-halves); block = 128co x 128px.
// Wave: 4 co-tiles x 4 px-tiles of 16x16x32 MFMA.
// grid.x = b * nCoBlk * 2 * nSlice ; part layout [nSlice][B8][Cout][256]
// ---------------------------------------------------------------------------
__global__ __launch_bounds__(256, 2) void conv3x3_mfma(
    const float* __restrict__ in,        // [B8, Cin, 16, 16]
    const unsigned short* __restrict__ wT, // [9, Cout, Cin] bf16
    float* __restrict__ part, int Cin, int Cout, int nCoBlk, int nSlice)
{
  int t = blockIdx.x;
  int slice = t % nSlice; t /= nSlice;
  int ph = t & 1; t >>= 1;
  int cb = t % nCoBlk; t /= nCoBlk;
  int b = t;
  int ciSlice = Cin / nSlice;
  int nTiles = ciSlice >> 5;

  __shared__ unsigned short sIn[10 * 18 * 40];

  int tid = threadIdx.x;
  int lane = tid & 63, wave = tid >> 6;
  int wc = wave >> 1, wp = wave & 1;
  int l15 = lane & 15, q = lane >> 4;

  // zero whole LDS once: halo rows/cols stay zero forever
  for (int i = tid; i < (10 * 18 * 40) / 2; i += 256) ((unsigned int*)sIn)[i] = 0u;

  floatx4 acc[4][4];
#pragma unroll
  for (int ct = 0; ct < 4; ++ct)
#pragma unroll
    for (int pt = 0; pt < 4; ++pt) acc[ct][pt] = (floatx4){0.f, 0.f, 0.f, 0.f};

  int coBase = cb * 128 + wc * 64;
  const float* inb = in + (size_t)b * Cin * 256;
  int gr0 = ph * 7;      // first staged global row
  int sr0 = 1 - ph;      // its LDS row

  for (int ct2 = 0; ct2 < nTiles; ++ct2) {
    int ci0 = slice * ciSlice + ct2 * 32;
    __syncthreads();
    // stage 9 rows x 16 cols x 32 ci, convert fp32->bf16
    for (int i = tid; i < 9 * 16 * 32; i += 256) {
      int px = i & 15;
      int r9 = i >> 4;
      int rr = r9 % 9;
      int ci = r9 / 9;
      float v = inb[(size_t)(ci0 + ci) * 256 + (gr0 + rr) * 16 + px];
      sIn[((sr0 + rr) * 18 + 1 + px) * 40 + ci] = f2bf(v);
    }
    __syncthreads();
#pragma unroll
    for (int ky = 0; ky < 3; ++ky) {
#pragma unroll
      for (int kx = 0; kx < 3; ++kx) {
        int tap = ky * 3 + kx;
        const unsigned short* wbase =
            wT + ((size_t)(tap * Cout + coBase + l15)) * Cin + ci0 + q * 8;
        short8 af[4];
#pragma unroll
        for (int ct = 0; ct < 4; ++ct)
          af[ct] = *(const short8*)(wbase + (size_t)ct * 16 * Cin);
        short8 bf[4];
#pragma unroll
        for (int pt = 0; pt < 4; ++pt) {
          int sRow = wp * 4 + pt + ky;
          int sCol = l15 + kx;
          bf[pt] = *(const short8*)&sIn[(sRow * 18 + sCol) * 40 + q * 8];
        }
#pragma unroll
        for (int ct = 0; ct < 4; ++ct)
#pragma unroll
          for (int pt = 0; pt < 4; ++pt)
            acc[ct][pt] = __builtin_amdgcn_mfma_f32_16x16x32_bf16(
                af[ct], bf[pt], acc[ct][pt], 0, 0, 0);
      }
    }
  }

  float* po = part + ((size_t)(slice * B8 + b) * Cout) * 256;
#pragma unroll
  for (int ct = 0; ct < 4; ++ct) {
#pragma unroll
    for (int pt = 0; pt < 4; ++pt) {
      int co = coBase + ct * 16 + q * 4;
      int px = ph * 128 + wp * 64 + pt * 16 + l15;
#pragma unroll
      for (int r = 0; r < 4; ++r)
        po[(size_t)(co + r) * 256 + px] = acc[ct][pt][r];
    }
  }
}

// ---------------------------------------------------------------------------
// sum K-slices + BN + ReLU; optional global-average-pool broadcast write into
// channels [Cout, 2*Cout) of out. grid.x = B8*Cout, block=256.
// ---------------------------------------------------------------------------
__global__ __launch_bounds__(256) void combine_bn_relu(
    const float* __restrict__ part, const float* __restrict__ scale,
    const float* __restrict__ shift, float* __restrict__ out,
    int Cout, int nSlice, int outStride, int doPool)
{
  int c = blockIdx.x % Cout, b = blockIdx.x / Cout;
  int tid = threadIdx.x;
  float s = 0.0f;
  for (int sl = 0; sl < nSlice; ++sl)
    s += part[(((size_t)sl * B8 + b) * Cout + c) * 256 + tid];
  float v = fmaf(s, scale[c], shift[c]);
  v = v > 0.0f ? v : 0.0f;
  out[((size_t)b * outStride + c) * 256 + tid] = v;
  if (doPool) {
    __shared__ float red[4];
    float w = v;
#pragma unroll
    for (int off = 32; off > 0; off >>= 1) w += __shfl_down(w, off, 64);
    if ((tid & 63) == 0) red[tid >> 6] = w;
    __syncthreads();
    float m = (red[0] + red[1] + red[2] + red[3]) * (1.0f / 256.0f);
    out[((size_t)b * outStride + Cout + c) * 256 + tid] = m;
  }
}

// ---------------------------------------------------------------------------
// conv3x3 256->48 + BN + ReLU on 128x128. grid.x = B8*64*3 (3 cout groups).
// ---------------------------------------------------------------------------
__global__ __launch_bounds__(256) void conv3x3_hi(
    const float* __restrict__ in, const float* __restrict__ wgt,
    const float* __restrict__ scale, const float* __restrict__ shift,
    float* __restrict__ out)
{
  int t = blockIdx.x;
  int cog = t % 3;
  int tile = (t / 3) & 63;
  int b = t / 192;
  int ty0 = (tile >> 3) << 4, tx0 = (tile & 7) << 4;
  __shared__ float sIn[4][324];
  int tid = threadIdx.x;
  int px = tid & 15, py = tid >> 4;
  float acc[16];
#pragma unroll
  for (int co = 0; co < 16; ++co) acc[co] = 0.0f;
  const float* inb = in + (size_t)b * 256 * 16384;
  const float* wb = wgt + (size_t)(cog * 16) * 256 * 9;

  for (int cg = 0; cg < 256; cg += 4) {
    __syncthreads();
    for (int i = tid; i < 1296; i += 256) {
      int p = i / 324;
      int r = i - p * 324;
      int rr = r / 18, cc = r - rr * 18;
      int gy = ty0 + rr - 1, gx = tx0 + cc - 1;
      float v = 0.0f;
      if ((unsigned)gy < 128u && (unsigned)gx < 128u)
        v = inb[(size_t)(cg + p) * 16384 + gy * 128 + gx];
      ((float*)sIn)[i] = v;
    }
    __syncthreads();
#pragma unroll
    for (int p = 0; p < 4; ++p) {
      float in9[9];
#pragma unroll
      for (int ky = 0; ky < 3; ++ky)
#pragma unroll
        for (int kx = 0; kx < 3; ++kx)
          in9[ky * 3 + kx] = sIn[p][(py + ky) * 18 + px + kx];
      int ci = cg + p;
#pragma unroll
      for (int co = 0; co < 16; ++co) {
        const float* wp = wb + ((size_t)co * 256 + ci) * 9;
#pragma unroll
        for (int k = 0; k < 9; ++k) acc[co] = fmaf(in9[k], wp[k], acc[co]);
      }
    }
  }
  int oy = ty0 + py, ox = tx0 + px;
#pragma unroll
  for (int co = 0; co < 16; ++co) {
    int c = cog * 16 + co;
    float v = fmaf(acc[co], scale[c], shift[c]);
    v = v > 0.0f ? v : 0.0f;
    out[((size_t)b * 48 + c) * 16384 + oy * 128 + ox] = v;
  }
}

// ---------------------------------------------------------------------------
__global__ __launch_bounds__(256) void conv1x1_lo(
    const float* __restrict__ in, const float* __restrict__ wgt,
    const float* __restrict__ bias, float* __restrict__ out)
{
  int b = blockIdx.x >> 6;
  int px = ((blockIdx.x & 63) << 8) + threadIdx.x;
  float acc[16];
#pragma unroll
  for (int co = 0; co < 16; ++co) acc[co] = 0.0f;
#pragma unroll 4
  for (int ci = 0; ci < 48; ++ci) {
    float xv = in[((size_t)b * 48 + ci) * 16384 + px];
#pragma unroll
    for (int co = 0; co < 16; ++co) acc[co] = fmaf(xv, wgt[co * 48 + ci], acc[co]);
  }
#pragma unroll
  for (int co = 0; co < 16; ++co)
    out[((size_t)b * 16 + co) * 16384 + px] = acc[co] + bias[co];
}

// ---------------------------------------------------------------------------
__global__ __launch_bounds__(256) void conv1x1_hyper(
    const float* __restrict__ x2, const float* __restrict__ wgt,
    const float* __restrict__ bias, float* __restrict__ hyper)
{
  int cog = blockIdx.x % 154, b = blockIdx.x / 154;
  int co0 = cog * 32;
  int tid = threadIdx.x;
  float acc[32];
#pragma unroll
  for (int i = 0; i < 32; ++i) acc[i] = 0.0f;
  const float* xb = x2 + (size_t)b * 1024 * 256 + tid;
#pragma unroll 4
  for (int ci = 0; ci < 1024; ++ci) {
    float xv = xb[(size_t)ci * 256];
    const float* wp = wgt + (size_t)co0 * 1024 + ci;
#pragma unroll
    for (int co = 0; co < 32; ++co) acc[co] = fmaf(xv, wp[(size_t)co * 1024], acc[co]);
  }
  float* hb = hyper + ((size_t)b * 4928 + co0) * 256 + tid;
#pragma unroll
  for (int co = 0; co < 32; ++co) hb[co * 256] = acc[co] + bias[co0 + co];
}

// ---------------------------------------------------------------------------
// dynamic per-pixel MLP: 18 -> 16 -> 16 -> 256 (see round-0 comments).
// ---------------------------------------------------------------------------
__global__ __launch_bounds__(256) void dyn_mlp(
    const float* __restrict__ hyper, const float* __restrict__ c1,
    const float* __restrict__ catS, const float* __restrict__ catB,
    float* __restrict__ out)
{
  int t = blockIdx.x;
  int q = t & 3;
  int h = (t >> 2) & 15;
  int b = t >> 6;
  int tid = threadIdx.x;
  int xf = tid & 127, r2 = tid >> 7;
  int w = xf >> 3;

  __shared__ float smem[16 * 578];
  __shared__ float sB2[16 * 33];

  const float* hypb = hyper + (size_t)b * 4928 * 256 + h * 16;

  for (int i = tid; i < 576 * 16; i += 256) {
    int ch = i >> 4, ww = i & 15;
    smem[ww * 578 + ch] = hypb[(size_t)ch * 256 + ww];
  }

  float cs[18], cb[18];
#pragma unroll
  for (int i = 0; i < 18; ++i) { cs[i] = catS[i]; cb[i] = catB[i]; }

  float inpv[4][18];
  int yf0 = h * 8 + r2 * 4;
  float cx = (float)(xf & 7) * 0.125f;
#pragma unroll
  for (int k = 0; k < 4; ++k) {
    inpv[k][0] = fmaf(cx, cs[0], cb[0]);
    inpv[k][1] = fmaf((float)((yf0 + k) & 7) * 0.125f, cs[1], cb[1]);
#pragma unroll
    for (int ci = 0; ci < 16; ++ci) {
      float v = c1[((size_t)b * 16 + ci) * 16384 + (size_t)(yf0 + k) * 128 + xf];
      inpv[k][2 + ci] = fmaf(v, cs[2 + ci], cb[2 + ci]);
    }
  }
  __syncthreads();

  const float* sw = smem + w * 578;
  float h0v[4][16];
  {
    const float2* w0p = (const float2*)sw;
#pragma unroll
    for (int co = 0; co < 16; ++co) {
      float a0 = sw[288 + co], a1 = a0, a2 = a0, a3 = a0;
#pragma unroll
      for (int c2 = 0; c2 < 9; ++c2) {
        float2 wv = w0p[co * 9 + c2];
        a0 = fmaf(wv.x, inpv[0][2 * c2], a0); a0 = fmaf(wv.y, inpv[0][2 * c2 + 1], a0);
        a1 = fmaf(wv.x, inpv[1][2 * c2], a1); a1 = fmaf(wv.y, inpv[1][2 * c2 + 1], a1);
        a2 = fmaf(wv.x, inpv[2][2 * c2], a2); a2 = fmaf(wv.y, inpv[2][2 * c2 + 1], a2);
        a3 = fmaf(wv.x, inpv[3][2 * c2], a3); a3 = fmaf(wv.y, inpv[3][2 * c2 + 1], a3);
      }
      h0v[0][co] = fmaxf(a0, 0.0f); h0v[1][co] = fmaxf(a1, 0.0f);
      h0v[2][co] = fmaxf(a2, 0.0f); h0v[3][co] = fmaxf(a3, 0.0f);
    }
  }
  float h1v[4][16];
  {
    const float2* w1p = (const float2*)(sw + 304);
#pragma unroll
    for (int co = 0; co < 16; ++co) {
      float a0 = sw[560 + co], a1 = a0, a2 = a0, a3 = a0;
#pragma unroll
      for (int c2 = 0; c2 < 8; ++c2) {
        float2 wv = w1p[co * 8 + c2];
        a0 = fmaf(wv.x, h0v[0][2 * c2], a0); a0 = fmaf(wv.y, h0v[0][2 * c2 + 1], a0);
        a1 = fmaf(wv.x, h0v[1][2 * c2], a1); a1 = fmaf(wv.y, h0v[1][2 * c2 + 1], a1);
        a2 = fmaf(wv.x, h0v[2][2 * c2], a2); a2 = fmaf(wv.y, h0v[2][2 * c2 + 1], a2);
        a3 = fmaf(wv.x, h0v[3][2 * c2], a3); a3 = fmaf(wv.y, h0v[3][2 * c2 + 1], a3);
      }
      h1v[0][co] = fmaxf(a0, 0.0f); h1v[1][co] = fmaxf(a1, 0.0f);
      h1v[2][co] = fmaxf(a2, 0.0f); h1v[3][co] = fmaxf(a3, 0.0f);
    }
  }

  for (int chunk = 0; chunk < 2; ++chunk) {
    int po0 = q * 64 + chunk * 32;
    __syncthreads();
    for (int i = tid; i < 8192; i += 256) {
      int ch = i >> 4, ww = i & 15;
      smem[ww * 518 + ch] = hypb[(size_t)(576 + po0 * 16 + ch) * 256 + ww];
    }
    for (int i = tid; i < 512; i += 256) {
      int po = i >> 4, ww = i & 15;
      sB2[ww * 33 + po] = hypb[(size_t)(4672 + po0 + po) * 256 + ww];
    }
    __syncthreads();
    const float2* w2p = (const float2*)(smem + w * 518);
    const float* sb2 = sB2 + w * 33;
#pragma unroll 4
    for (int po = 0; po < 32; ++po) {
      float a0 = sb2[po], a1 = a0, a2 = a0, a3 = a0;
#pragma unroll
      for (int c2 = 0; c2 < 8; ++c2) {
        float2 wv = w2p[po * 8 + c2];
        a0 = fmaf(wv.x, h1v[0][2 * c2], a0); a0 = fmaf(wv.y, h1v[0][2 * c2 + 1], a0);
        a1 = fmaf(wv.x, h1v[1][2 * c2], a1); a1 = fmaf(wv.y, h1v[1][2 * c2 + 1], a1);
        a2 = fmaf(wv.x, h1v[2][2 * c2], a2); a2 = fmaf(wv.y, h1v[2][2 * c2 + 1], a2);
        a3 = fmaf(wv.x, h1v[3][2 * c2], a3); a3 = fmaf(wv.y, h1v[3][2 * c2 + 1], a3);
      }
      size_t ob = ((size_t)b * 256 + po0 + po) * 16384 + (size_t)yf0 * 128 + xf;
      out[ob] = a0; out[ob + 128] = a1; out[ob + 256] = a2; out[ob + 384] = a3;
    }
  }
}

// ---------------------------------------------------------------------------
extern "C" void kernel_launch(void* const* d_in, const int* in_sizes, int n_in,
                              void* d_out, int out_size, void* d_ws, size_t ws_size,
                              hipStream_t stream) {
  const float* res5 = (const float*)d_in[0];
  const float* res2 = (const float*)d_in[1];
  const float* bw   = (const float*)d_in[2];
  const float* bn1s = (const float*)d_in[3];
  const float* bn1b = (const float*)d_in[4];
  const float* c0w  = (const float*)d_in[5];
  const float* bn2s = (const float*)d_in[6];
  const float* bn2b = (const float*)d_in[7];
  const float* cls1w = (const float*)d_in[8];
  const float* cls1b = (const float*)d_in[9];
  const float* c1aw = (const float*)d_in[10];
  const float* bn3s = (const float*)d_in[11];
  const float* bn3b = (const float*)d_in[12];
  const float* c1bw = (const float*)d_in[13];
  const float* c1bb = (const float*)d_in[14];
  const float* catS = (const float*)d_in[15];
  const float* catB = (const float*)d_in[16];
  float* out = (float*)d_out;
  float* ws = (float*)d_ws;

  // ws layout (float offsets), with lifetime-based aliasing (peak 88 MB):
  //  [0,        9437184)  wT1+wT2 bf16 (9.44M ushort each)   -- dead after conv2
  //  [9437184, 17825792)  partial (8.39M)                    -- dead after combines
  //  [17825792,19922944)  x2cat                              -- dead after conv2
  //  [19922944,22020096)  x2
  //  hyper  -> alias [9437184, 19529728)
  //  c1mid  -> alias [0, 6291456) ; c1 -> [6291456, 8388608)
  unsigned short* wT1 = (unsigned short*)ws;                 // 512*2048*9
  unsigned short* wT2 = wT1 + 9437184;                       // 1024*1024*9
  float* partial = ws + 9437184;
  float* x2cat   = ws + 17825792;
  float* x2      = ws + 19922944;
  float* hyper   = ws + 9437184;
  float* c1mid   = ws;
  float* c1      = ws + 6291456;

  // weight transforms (bf16, tap-major)
  wtransform<<<(512 * 2048 + 255) / 256, 256, 0, stream>>>(bw, wT1, 512, 2048);
  wtransform<<<(1024 * 1024 + 255) / 256, 256, 0, stream>>>(c0w, wT2, 1024, 1024);

  // bottleneck conv (2048->512) MFMA, 8 K-slices: grid = 8b*4co*2px*8K
  conv3x3_mfma<<<8 * 4 * 2 * 8, 256, 0, stream>>>(res5, wT1, partial, 2048, 512, 4, 8);
  combine_bn_relu<<<8 * 512, 256, 0, stream>>>(partial, bn1s, bn1b, x2cat, 512, 8, 1024, 1);
  // cls0 conv (1024->1024) MFMA, 4 K-slices: grid = 8b*8co*2px*4K
  conv3x3_mfma<<<8 * 8 * 2 * 4, 256, 0, stream>>>(x2cat, wT2, partial, 1024, 1024, 8, 4);
  combine_bn_relu<<<8 * 1024, 256, 0, stream>>>(partial, bn2s, bn2b, x2, 1024, 4, 1024, 0);
  // cls1 1x1 (1024->4928)
  conv1x1_hyper<<<8 * 154, 256, 0, stream>>>(x2, cls1w, cls1b, hyper);
  // low-level branch
  conv3x3_hi<<<8 * 64 * 3, 256, 0, stream>>>(res2, c1aw, bn3s, bn3b, c1mid);
  conv1x1_lo<<<8 * 64, 256, 0, stream>>>(c1mid, c1bw, c1bb, c1);
  // dynamic MLP
  dyn_mlp<<<8 * 16 * 4, 256, 0, stream>>>(hyper, c1, catS, catB, out);
}

// Round 3
// 832.292 us; speedup vs baseline: 5.1085x; 2.4605x over previous
//
#include <hip/hip_runtime.h>

#define B8 8

typedef __attribute__((ext_vector_type(8))) short short8;
typedef __attribute__((ext_vector_type(4))) float floatx4;

static __device__ __forceinline__ unsigned short f2bf(float f) {
  unsigned int u = __float_as_uint(f);
  unsigned int r = (u + 0x7fffu + ((u >> 16) & 1u)) >> 16;
  return (unsigned short)r;
}

// ---------------------------------------------------------------------------
// weight transform: w[co][ci][3][3] fp32 -> wT[tap][co][ci] bf16
// ---------------------------------------------------------------------------
__global__ __launch_bounds__(256) void wtransform(
    const float* __restrict__ w, unsigned short* __restrict__ wT,
    int Cout, int Cin)
{
  int idx = blockIdx.x * 256 + threadIdx.x;
  if (idx >= Cout * Cin) return;
  int ci = idx % Cin, co = idx / Cin;
  const float* s = w + (size_t)idx * 9;
#pragma unroll
  for (int t = 0; t < 9; ++t)
    wT[((size_t)t * Cout + co) * Cin + ci] = f2bf(s[t]);
}

// elementwise fp32 -> bf16 (for cls1 1x1 weights, layout preserved)
__global__ __launch_bounds__(256) void cvt_bf16(
    const float* __restrict__ w, unsigned short* __restrict__ o, int n)
{
  int i = blockIdx.x * 256 + threadIdx.x;
  if (i < n) o[i] = f2bf(w[i]);
}

// ---------------------------------------------------------------------------
// bf16 MFMA conv3x3 on 16x16 spatial, SAME zero pad, K-sliced.
// D[m=co][n=px]; A = wT[tap][co][ci] from global; B = pixels in LDS.
// Block 256 thr = 4 waves (2 co-halves x 2 px-halves), 128co x 128px.
// grid.x = b * nCoBlk * 2 * nSlice ; part layout [nSlice][B8][Cout][256]
// ---------------------------------------------------------------------------
__global__ __launch_bounds__(256, 2) void conv3x3_mfma(
    const void* __restrict__ inv,          // [B8, Cin, 16, 16] fp32 or bf16
    const unsigned short* __restrict__ wT, // [9, Cout, Cin] bf16
    float* __restrict__ part, int Cin, int Cout, int nCoBlk, int nSlice,
    int inBf16)
{
  int t = blockIdx.x;
  int slice = t % nSlice; t /= nSlice;
  int ph = t & 1; t >>= 1;
  int cb = t % nCoBlk; t /= nCoBlk;
  int b = t;
  int ciSlice = Cin / nSlice;
  int nTiles = ciSlice >> 5;

  __shared__ unsigned short sIn[10 * 18 * 40];

  int tid = threadIdx.x;
  int lane = tid & 63, wave = tid >> 6;
  int wc = wave >> 1, wp = wave & 1;
  int l15 = lane & 15, q = lane >> 4;

  for (int i = tid; i < (10 * 18 * 40) / 2; i += 256) ((unsigned int*)sIn)[i] = 0u;

  floatx4 acc[4][4];
#pragma unroll
  for (int ct = 0; ct < 4; ++ct)
#pragma unroll
    for (int pt = 0; pt < 4; ++pt) acc[ct][pt] = (floatx4){0.f, 0.f, 0.f, 0.f};

  int coBase = cb * 128 + wc * 64;
  int gr0 = ph * 7;
  int sr0 = 1 - ph;

  for (int ct2 = 0; ct2 < nTiles; ++ct2) {
    int ci0 = slice * ciSlice + ct2 * 32;
    __syncthreads();
    if (inBf16) {
      const unsigned short* inb = (const unsigned short*)inv + (size_t)b * Cin * 256;
      for (int i = tid; i < 9 * 16 * 32; i += 256) {
        int px = i & 15;
        int r9 = i >> 4;
        int rr = r9 % 9;
        int ci = r9 / 9;
        sIn[((sr0 + rr) * 18 + 1 + px) * 40 + ci] =
            inb[(size_t)(ci0 + ci) * 256 + (gr0 + rr) * 16 + px];
      }
    } else {
      const float* inb = (const float*)inv + (size_t)b * Cin * 256;
      for (int i = tid; i < 9 * 16 * 32; i += 256) {
        int px = i & 15;
        int r9 = i >> 4;
        int rr = r9 % 9;
        int ci = r9 / 9;
        float v = inb[(size_t)(ci0 + ci) * 256 + (gr0 + rr) * 16 + px];
        sIn[((sr0 + rr) * 18 + 1 + px) * 40 + ci] = f2bf(v);
      }
    }
    __syncthreads();
#pragma unroll
    for (int ky = 0; ky < 3; ++ky) {
#pragma unroll
      for (int kx = 0; kx < 3; ++kx) {
        int tap = ky * 3 + kx;
        const unsigned short* wbase =
            wT + ((size_t)(tap * Cout + coBase + l15)) * Cin + ci0 + q * 8;
        short8 af[4];
#pragma unroll
        for (int ct = 0; ct < 4; ++ct)
          af[ct] = *(const short8*)(wbase + (size_t)ct * 16 * Cin);
        short8 bf[4];
#pragma unroll
        for (int pt = 0; pt < 4; ++pt) {
          int sRow = wp * 4 + pt + ky;
          int sCol = l15 + kx;
          bf[pt] = *(const short8*)&sIn[(sRow * 18 + sCol) * 40 + q * 8];
        }
#pragma unroll
        for (int ct = 0; ct < 4; ++ct)
#pragma unroll
          for (int pt = 0; pt < 4; ++pt)
            acc[ct][pt] = __builtin_amdgcn_mfma_f32_16x16x32_bf16(
                af[ct], bf[pt], acc[ct][pt], 0, 0, 0);
      }
    }
  }

  float* po = part + ((size_t)(slice * B8 + b) * Cout) * 256;
#pragma unroll
  for (int ct = 0; ct < 4; ++ct) {
#pragma unroll
    for (int pt = 0; pt < 4; ++pt) {
      int co = coBase + ct * 16 + q * 4;
      int px = ph * 128 + wp * 64 + pt * 16 + l15;
#pragma unroll
      for (int r = 0; r < 4; ++r)
        po[(size_t)(co + r) * 256 + px] = acc[ct][pt][r];
    }
  }
}

// ---------------------------------------------------------------------------
// conv1 combine: sum 8 K-slices + BN + ReLU -> x2cat bf16, plus pooled-mean
// broadcast into channels [512,1024). grid.x = B8*512, block=256.
// ---------------------------------------------------------------------------
__global__ __launch_bounds__(256) void combine1(
    const float* __restrict__ part, const float* __restrict__ scale,
    const float* __restrict__ shift, unsigned short* __restrict__ out,
    int Cout, int nSlice, int outStride)
{
  int c = blockIdx.x % Cout, b = blockIdx.x / Cout;
  int tid = threadIdx.x;
  float s = 0.0f;
  for (int sl = 0; sl < nSlice; ++sl)
    s += part[(((size_t)sl * B8 + b) * Cout + c) * 256 + tid];
  float v = fmaf(s, scale[c], shift[c]);
  v = v > 0.0f ? v : 0.0f;
  out[((size_t)b * outStride + c) * 256 + tid] = f2bf(v);
  __shared__ float red[4];
  float w = v;
#pragma unroll
  for (int off = 32; off > 0; off >>= 1) w += __shfl_down(w, off, 64);
  if ((tid & 63) == 0) red[tid >> 6] = w;
  __syncthreads();
  float m = (red[0] + red[1] + red[2] + red[3]) * (1.0f / 256.0f);
  out[((size_t)b * outStride + Cout + c) * 256 + tid] = f2bf(m);
}

// ---------------------------------------------------------------------------
// conv2 combine: sum 4 K-slices + BN + ReLU -> x2T bf16 TRANSPOSED [b][px][ci]
// grid.x = 8b * 16pxg * 4cg ; block 256 = (c16 = tid>>4, px16 = tid&15).
// ---------------------------------------------------------------------------
__global__ __launch_bounds__(256) void combine2T(
    const float* __restrict__ part, const float* __restrict__ scale,
    const float* __restrict__ shift, unsigned short* __restrict__ x2T)
{
  int t = blockIdx.x;
  int cg = t & 3;
  int pxg = (t >> 2) & 15;
  int b = t >> 6;
  int c16 = threadIdx.x >> 4, px16 = threadIdx.x & 15;
  int px = pxg * 16 + px16;
#pragma unroll
  for (int k = 0; k < 4; ++k) {
    int cBase = cg * 256 + k * 64 + c16 * 4;
    unsigned short v4[4];
#pragma unroll
    for (int j = 0; j < 4; ++j) {
      int c = cBase + j;
      float s = 0.0f;
#pragma unroll
      for (int sl = 0; sl < 4; ++sl)
        s += part[(((size_t)sl * B8 + b) * 1024 + c) * 256 + px];
      float v = fmaf(s, scale[c], shift[c]);
      v4[j] = f2bf(v > 0.0f ? v : 0.0f);
    }
    *(ushort2*)&x2T[((size_t)b * 256 + px) * 1024 + cBase] =
        *(ushort2*)&v4[0];
    *(ushort2*)&x2T[((size_t)b * 256 + px) * 1024 + cBase + 2] =
        *(ushort2*)&v4[2];
  }
}

// ---------------------------------------------------------------------------
// cls1 1x1 (1024->4928) as register-only MFMA GEMM. Per batch:
// D[4928co x 256px] = W[4928x1024] * X^T. A & B frags straight from global
// (both 16B-contiguous along ci). grid.x = 77 coBlk * 8 b, block = 4 waves.
// ---------------------------------------------------------------------------
__global__ __launch_bounds__(256, 2) void hyper_gemm(
    const unsigned short* __restrict__ wH,  // [4928,1024] bf16
    const unsigned short* __restrict__ x2T, // [8,256,1024] bf16
    const float* __restrict__ bias,         // [4928]
    float* __restrict__ hyper)              // [8,4928,256] fp32
{
  int cb = blockIdx.x % 77, b = blockIdx.x / 77;
  int tid = threadIdx.x;
  int lane = tid & 63, w = tid >> 6;
  int l15 = lane & 15, q = lane >> 4;

  floatx4 acc[4][4];
#pragma unroll
  for (int ct = 0; ct < 4; ++ct)
#pragma unroll
    for (int pt = 0; pt < 4; ++pt) acc[ct][pt] = (floatx4){0.f, 0.f, 0.f, 0.f};

  const unsigned short* wp0 = wH + ((size_t)(cb * 64 + l15)) * 1024 + q * 8;
  const unsigned short* xp0 =
      x2T + ((size_t)(b * 256 + w * 64 + l15)) * 1024 + q * 8;

  for (int ci0 = 0; ci0 < 1024; ci0 += 32) {
    short8 af[4], bf[4];
#pragma unroll
    for (int ct = 0; ct < 4; ++ct)
      af[ct] = *(const short8*)(wp0 + (size_t)ct * 16 * 1024 + ci0);
#pragma unroll
    for (int pt = 0; pt < 4; ++pt)
      bf[pt] = *(const short8*)(xp0 + (size_t)pt * 16 * 1024 + ci0);
#pragma unroll
    for (int ct = 0; ct < 4; ++ct)
#pragma unroll
      for (int pt = 0; pt < 4; ++pt)
        acc[ct][pt] = __builtin_amdgcn_mfma_f32_16x16x32_bf16(
            af[ct], bf[pt], acc[ct][pt], 0, 0, 0);
  }

#pragma unroll
  for (int ct = 0; ct < 4; ++ct) {
    int co = cb * 64 + ct * 16 + q * 4;
#pragma unroll
    for (int pt = 0; pt < 4; ++pt) {
      int px = w * 64 + pt * 16 + l15;
#pragma unroll
      for (int r = 0; r < 4; ++r)
        hyper[((size_t)b * 4928 + co + r) * 256 + px] = acc[ct][pt][r] + bias[co + r];
    }
  }
}

// ---------------------------------------------------------------------------
// conv3x3 256->48 + BN + ReLU on 128x128 via bf16 MFMA.
// Block = one 16x16 spatial tile, all 48 couts. 4 waves x 4 rows each.
// LDS: 18x18 halo x 32ci (pixel-major, ciPad 40). grid.x = 8b * 64 tiles.
// ---------------------------------------------------------------------------
__global__ __launch_bounds__(256, 2) void conv3x3_hi_mfma(
    const float* __restrict__ in,          // [B8,256,128,128]
    const unsigned short* __restrict__ wT, // [9,48,256] bf16
    const float* __restrict__ scale, const float* __restrict__ shift,
    float* __restrict__ out)               // [B8,48,128,128]
{
  int t = blockIdx.x;
  int tile = t & 63;
  int b = t >> 6;
  int ty0 = (tile >> 3) << 4, tx0 = (tile & 7) << 4;

  __shared__ unsigned short sIn[18 * 18 * 40];

  int tid = threadIdx.x;
  int lane = tid & 63, w = tid >> 6;
  int l15 = lane & 15, q = lane >> 4;

  // slot precompute (2 slots/thread max; 324 halo slots)
  int slotA = tid;
  int rowA = slotA / 18, colA = slotA % 18;
  int gyA = ty0 + rowA - 1, gxA = tx0 + colA - 1;
  bool vA = (unsigned)gyA < 128u && (unsigned)gxA < 128u;
  const float* gA = in + (size_t)b * 256 * 16384 + (vA ? (gyA * 128 + gxA) : 0);
  int slotB = 256 + tid;
  bool hasB = tid < 68;
  int rowB = slotB / 18, colB = slotB % 18;
  int gyB = ty0 + rowB - 1, gxB = tx0 + colB - 1;
  bool vB = hasB && (unsigned)gyB < 128u && (unsigned)gxB < 128u;
  const float* gB = in + (size_t)b * 256 * 16384 + (vB ? (gyB * 128 + gxB) : 0);

  floatx4 acc[3][4];
#pragma unroll
  for (int ct = 0; ct < 3; ++ct)
#pragma unroll
    for (int pt = 0; pt < 4; ++pt) acc[ct][pt] = (floatx4){0.f, 0.f, 0.f, 0.f};

  for (int ci0 = 0; ci0 < 256; ci0 += 32) {
    __syncthreads();
    unsigned int* sU = (unsigned int*)sIn;
#pragma unroll 4
    for (int cp = 0; cp < 16; ++cp) {
      float a0 = vA ? gA[(size_t)(ci0 + 2 * cp) * 16384] : 0.0f;
      float a1 = vA ? gA[(size_t)(ci0 + 2 * cp + 1) * 16384] : 0.0f;
      sU[slotA * 20 + cp] = (unsigned)f2bf(a0) | ((unsigned)f2bf(a1) << 16);
    }
    if (hasB) {
#pragma unroll 4
      for (int cp = 0; cp < 16; ++cp) {
        float a0 = vB ? gB[(size_t)(ci0 + 2 * cp) * 16384] : 0.0f;
        float a1 = vB ? gB[(size_t)(ci0 + 2 * cp + 1) * 16384] : 0.0f;
        sU[slotB * 20 + cp] = (unsigned)f2bf(a0) | ((unsigned)f2bf(a1) << 16);
      }
    }
    __syncthreads();
#pragma unroll
    for (int ky = 0; ky < 3; ++ky) {
#pragma unroll
      for (int kx = 0; kx < 3; ++kx) {
        int tap = ky * 3 + kx;
        const unsigned short* wbase =
            wT + ((size_t)(tap * 48 + l15)) * 256 + ci0 + q * 8;
        short8 af[3];
#pragma unroll
        for (int ct = 0; ct < 3; ++ct)
          af[ct] = *(const short8*)(wbase + (size_t)ct * 16 * 256);
        short8 bf[4];
#pragma unroll
        for (int pt = 0; pt < 4; ++pt) {
          int sRow = w * 4 + pt + ky;
          int sCol = l15 + kx;
          bf[pt] = *(const short8*)&sIn[(sRow * 18 + sCol) * 40 + q * 8];
        }
#pragma unroll
        for (int ct = 0; ct < 3; ++ct)
#pragma unroll
          for (int pt = 0; pt < 4; ++pt)
            acc[ct][pt] = __builtin_amdgcn_mfma_f32_16x16x32_bf16(
                af[ct], bf[pt], acc[ct][pt], 0, 0, 0);
      }
    }
  }

#pragma unroll
  for (int ct = 0; ct < 3; ++ct) {
#pragma unroll
    for (int pt = 0; pt < 4; ++pt) {
      int oy = ty0 + w * 4 + pt, ox = tx0 + l15;
#pragma unroll
      for (int r = 0; r < 4; ++r) {
        int c = ct * 16 + q * 4 + r;
        float v = fmaf(acc[ct][pt][r], scale[c], shift[c]);
        v = v > 0.0f ? v : 0.0f;
        out[((size_t)b * 48 + c) * 16384 + oy * 128 + ox] = v;
      }
    }
  }
}

// ---------------------------------------------------------------------------
__global__ __launch_bounds__(256) void conv1x1_lo(
    const float* __restrict__ in, const float* __restrict__ wgt,
    const float* __restrict__ bias, float* __restrict__ out)
{
  int b = blockIdx.x >> 6;
  int px = ((blockIdx.x & 63) << 8) + threadIdx.x;
  float acc[16];
#pragma unroll
  for (int co = 0; co < 16; ++co) acc[co] = 0.0f;
#pragma unroll 4
  for (int ci = 0; ci < 48; ++ci) {
    float xv = in[((size_t)b * 48 + ci) * 16384 + px];
#pragma unroll
    for (int co = 0; co < 16; ++co) acc[co] = fmaf(xv, wgt[co * 48 + ci], acc[co]);
  }
#pragma unroll
  for (int co = 0; co < 16; ++co)
    out[((size_t)b * 16 + co) * 16384 + px] = acc[co] + bias[co];
}

// ---------------------------------------------------------------------------
// dynamic per-pixel MLP: 18 -> 16 -> 16 -> 256 (see round-0 comments).
// ---------------------------------------------------------------------------
__global__ __launch_bounds__(256) void dyn_mlp(
    const float* __restrict__ hyper, const float* __restrict__ c1,
    const float* __restrict__ catS, const float* __restrict__ catB,
    float* __restrict__ out)
{
  int t = blockIdx.x;
  int q = t & 3;
  int h = (t >> 2) & 15;
  int b = t >> 6;
  int tid = threadIdx.x;
  int xf = tid & 127, r2 = tid >> 7;
  int w = xf >> 3;

  __shared__ float smem[16 * 578];
  __shared__ float sB2[16 * 33];

  const float* hypb = hyper + (size_t)b * 4928 * 256 + h * 16;

  for (int i = tid; i < 576 * 16; i += 256) {
    int ch = i >> 4, ww = i & 15;
    smem[ww * 578 + ch] = hypb[(size_t)ch * 256 + ww];
  }

  float cs[18], cb[18];
#pragma unroll
  for (int i = 0; i < 18; ++i) { cs[i] = catS[i]; cb[i] = catB[i]; }

  float inpv[4][18];
  int yf0 = h * 8 + r2 * 4;
  float cx = (float)(xf & 7) * 0.125f;
#pragma unroll
  for (int k = 0; k < 4; ++k) {
    inpv[k][0] = fmaf(cx, cs[0], cb[0]);
    inpv[k][1] = fmaf((float)((yf0 + k) & 7) * 0.125f, cs[1], cb[1]);
#pragma unroll
    for (int ci = 0; ci < 16; ++ci) {
      float v = c1[((size_t)b * 16 + ci) * 16384 + (size_t)(yf0 + k) * 128 + xf];
      inpv[k][2 + ci] = fmaf(v, cs[2 + ci], cb[2 + ci]);
    }
  }
  __syncthreads();

  const float* sw = smem + w * 578;
  float h0v[4][16];
  {
    const float2* w0p = (const float2*)sw;
#pragma unroll
    for (int co = 0; co < 16; ++co) {
      float a0 = sw[288 + co], a1 = a0, a2 = a0, a3 = a0;
#pragma unroll
      for (int c2 = 0; c2 < 9; ++c2) {
        float2 wv = w0p[co * 9 + c2];
        a0 = fmaf(wv.x, inpv[0][2 * c2], a0); a0 = fmaf(wv.y, inpv[0][2 * c2 + 1], a0);
        a1 = fmaf(wv.x, inpv[1][2 * c2], a1); a1 = fmaf(wv.y, inpv[1][2 * c2 + 1], a1);
        a2 = fmaf(wv.x, inpv[2][2 * c2], a2); a2 = fmaf(wv.y, inpv[2][2 * c2 + 1], a2);
        a3 = fmaf(wv.x, inpv[3][2 * c2], a3); a3 = fmaf(wv.y, inpv[3][2 * c2 + 1], a3);
      }
      h0v[0][co] = fmaxf(a0, 0.0f); h0v[1][co] = fmaxf(a1, 0.0f);
      h0v[2][co] = fmaxf(a2, 0.0f); h0v[3][co] = fmaxf(a3, 0.0f);
    }
  }
  float h1v[4][16];
  {
    const float2* w1p = (const float2*)(sw + 304);
#pragma unroll
    for (int co = 0; co < 16; ++co) {
      float a0 = sw[560 + co], a1 = a0, a2 = a0, a3 = a0;
#pragma unroll
      for (int c2 = 0; c2 < 8; ++c2) {
        float2 wv = w1p[co * 8 + c2];
        a0 = fmaf(wv.x, h0v[0][2 * c2], a0); a0 = fmaf(wv.y, h0v[0][2 * c2 + 1], a0);
        a1 = fmaf(wv.x, h0v[1][2 * c2], a1); a1 = fmaf(wv.y, h0v[1][2 * c2 + 1], a1);
        a2 = fmaf(wv.x, h0v[2][2 * c2], a2); a2 = fmaf(wv.y, h0v[2][2 * c2 + 1], a2);
        a3 = fmaf(wv.x, h0v[3][2 * c2], a3); a3 = fmaf(wv.y, h0v[3][2 * c2 + 1], a3);
      }
      h1v[0][co] = fmaxf(a0, 0.0f); h1v[1][co] = fmaxf(a1, 0.0f);
      h1v[2][co] = fmaxf(a2, 0.0f); h1v[3][co] = fmaxf(a3, 0.0f);
    }
  }

  for (int chunk = 0; chunk < 2; ++chunk) {
    int po0 = q * 64 + chunk * 32;
    __syncthreads();
    for (int i = tid; i < 8192; i += 256) {
      int ch = i >> 4, ww = i & 15;
      smem[ww * 518 + ch] = hypb[(size_t)(576 + po0 * 16 + ch) * 256 + ww];
    }
    for (int i = tid; i < 512; i += 256) {
      int po = i >> 4, ww = i & 15;
      sB2[ww * 33 + po] = hypb[(size_t)(4672 + po0 + po) * 256 + ww];
    }
    __syncthreads();
    const float2* w2p = (const float2*)(smem + w * 518);
    const float* sb2 = sB2 + w * 33;
#pragma unroll 4
    for (int po = 0; po < 32; ++po) {
      float a0 = sb2[po], a1 = a0, a2 = a0, a3 = a0;
#pragma unroll
      for (int c2 = 0; c2 < 8; ++c2) {
        float2 wv = w2p[po * 8 + c2];
        a0 = fmaf(wv.x, h1v[0][2 * c2], a0); a0 = fmaf(wv.y, h1v[0][2 * c2 + 1], a0);
        a1 = fmaf(wv.x, h1v[1][2 * c2], a1); a1 = fmaf(wv.y, h1v[1][2 * c2 + 1], a1);
        a2 = fmaf(wv.x, h1v[2][2 * c2], a2); a2 = fmaf(wv.y, h1v[2][2 * c2 + 1], a2);
        a3 = fmaf(wv.x, h1v[3][2 * c2], a3); a3 = fmaf(wv.y, h1v[3][2 * c2 + 1], a3);
      }
      size_t ob = ((size_t)b * 256 + po0 + po) * 16384 + (size_t)yf0 * 128 + xf;
      out[ob] = a0; out[ob + 128] = a1; out[ob + 256] = a2; out[ob + 384] = a3;
    }
  }
}

// ---------------------------------------------------------------------------
extern "C" void kernel_launch(void* const* d_in, const int* in_sizes, int n_in,
                              void* d_out, int out_size, void* d_ws, size_t ws_size,
                              hipStream_t stream) {
  const float* res5 = (const float*)d_in[0];
  const float* res2 = (const float*)d_in[1];
  const float* bw   = (const float*)d_in[2];
  const float* bn1s = (const float*)d_in[3];
  const float* bn1b = (const float*)d_in[4];
  const float* c0w  = (const float*)d_in[5];
  const float* bn2s = (const float*)d_in[6];
  const float* bn2b = (const float*)d_in[7];
  const float* cls1w = (const float*)d_in[8];
  const float* cls1b = (const float*)d_in[9];
  const float* c1aw = (const float*)d_in[10];
  const float* bn3s = (const float*)d_in[11];
  const float* bn3b = (const float*)d_in[12];
  const float* c1bw = (const float*)d_in[13];
  const float* c1bb = (const float*)d_in[14];
  const float* catS = (const float*)d_in[15];
  const float* catB = (const float*)d_in[16];
  float* out = (float*)d_out;
  float* ws = (float*)d_ws;

  // ws layout (float offsets), lifetime-aliased, peak 25,296,896 fl = 101.2 MB
  // (<= 107.5 MB proven in round 0):
  unsigned short* wT2u  = (unsigned short*)(ws);             // [0, 4718592)
  unsigned short* x2cat = (unsigned short*)(ws + 4718592);   // 2,097,152 us
  unsigned short* wT48  = (unsigned short*)(ws + 4718592);   // alias (after conv2)
  unsigned short* x2T   = (unsigned short*)(ws + 5767168);   // 2,097,152 us
  float* hyper          = ws + 6815744;                      // 10,092,544 fl
  unsigned short* wT1u  = (unsigned short*)(ws + 6815744);   // alias (dead pre-hyper)
  float* partial        = ws + 16908288;                     // 8,388,608 fl
  unsigned short* wH    = (unsigned short*)(ws + 16908288);  // alias (after combine2T)
  float* c1mid          = ws + 16908288;                     // alias (after hyper_gemm)
  float* c1             = ws + 23199744;                     // 2,097,152 fl

  // conv weights -> bf16 tap-major
  wtransform<<<(512 * 2048 + 255) / 256, 256, 0, stream>>>(bw, wT1u, 512, 2048);
  wtransform<<<(1024 * 1024 + 255) / 256, 256, 0, stream>>>(c0w, wT2u, 1024, 1024);

  // bottleneck conv (2048->512), 8 K-slices
  conv3x3_mfma<<<8 * 4 * 2 * 8, 256, 0, stream>>>(res5, wT1u, partial, 2048, 512, 4, 8, 0);
  combine1<<<8 * 512, 256, 0, stream>>>(partial, bn1s, bn1b, x2cat, 512, 8, 1024);
  // cls0 conv (1024->1024), 4 K-slices, bf16 input
  conv3x3_mfma<<<8 * 8 * 2 * 4, 256, 0, stream>>>(x2cat, wT2u, partial, 1024, 1024, 8, 4, 1);
  combine2T<<<8 * 16 * 4, 256, 0, stream>>>(partial, bn2s, bn2b, x2T);
  // cls1 1x1 (1024->4928) MFMA  (wH aliases dead partial)
  cvt_bf16<<<(4928 * 1024 + 255) / 256, 256, 0, stream>>>(cls1w, wH, 4928 * 1024);
  hyper_gemm<<<77 * 8, 256, 0, stream>>>(wH, x2T, cls1b, hyper);
  // low-level branch (wT48 aliases dead x2cat; c1mid aliases dead wH/partial)
  wtransform<<<(48 * 256 + 255) / 256, 256, 0, stream>>>(c1aw, wT48, 48, 256);
  conv3x3_hi_mfma<<<8 * 64, 256, 0, stream>>>(res2, wT48, bn3s, bn3b, c1mid);
  conv1x1_lo<<<8 * 64, 256, 0, stream>>>(c1mid, c1bw, c1bb, c1);
  // dynamic MLP
  dyn_mlp<<<8 * 16 * 4, 256, 0, stream>>>(hyper, c1, catS, catB, out);
}

// Round 4
// 728.074 us; speedup vs baseline: 5.8397x; 1.1431x over previous
//
#include <hip/hip_runtime.h>

#define B8 8

typedef __attribute__((ext_vector_type(8))) short short8;
typedef __attribute__((ext_vector_type(4))) float floatx4;

static __device__ __forceinline__ unsigned short f2bf(float f) {
  unsigned int u = __float_as_uint(f);
  unsigned int r = (u + 0x7fffu + ((u >> 16) & 1u)) >> 16;
  return (unsigned short)r;
}

// ---------------------------------------------------------------------------
// weight transform: w[co][ci][3][3] fp32 -> wT[tap][co][ci] bf16
// ---------------------------------------------------------------------------
__global__ __launch_bounds__(256) void wtransform(
    const float* __restrict__ w, unsigned short* __restrict__ wT,
    int Cout, int Cin)
{
  int idx = blockIdx.x * 256 + threadIdx.x;
  if (idx >= Cout * Cin) return;
  int ci = idx % Cin, co = idx / Cin;
  const float* s = w + (size_t)idx * 9;
#pragma unroll
  for (int t = 0; t < 9; ++t)
    wT[((size_t)t * Cout + co) * Cin + ci] = f2bf(s[t]);
}

// elementwise fp32 -> bf16 (for cls1 1x1 weights, layout preserved)
__global__ __launch_bounds__(256) void cvt_bf16(
    const float* __restrict__ w, unsigned short* __restrict__ o, int n)
{
  int i = blockIdx.x * 256 + threadIdx.x;
  if (i < n) o[i] = f2bf(w[i]);
}

// ---------------------------------------------------------------------------
// bf16 MFMA conv3x3 on 16x16 spatial, SAME zero pad, K-sliced.
// D[m=co][n=px]; A = wT[tap][co][ci] from global; B = pixels in LDS.
// Software-pipelined: next chunk's 18 loads/thread prefetched into regs
// while current chunk's MFMAs run (grid-limited to 2 blocks/CU, so ILP
// must hide the staging latency).
// grid.x = b * nCoBlk * 2 * nSlice ; part layout [nSlice][B8][Cout][256]
// ---------------------------------------------------------------------------
__global__ __launch_bounds__(256, 2) void conv3x3_mfma(
    const void* __restrict__ inv,          // [B8, Cin, 16, 16] fp32 or bf16
    const unsigned short* __restrict__ wT, // [9, Cout, Cin] bf16
    float* __restrict__ part, int Cin, int Cout, int nCoBlk, int nSlice,
    int inBf16)
{
  int t = blockIdx.x;
  int slice = t % nSlice; t /= nSlice;
  int ph = t & 1; t >>= 1;
  int cb = t % nCoBlk; t /= nCoBlk;
  int b = t;
  int ciSlice = Cin / nSlice;
  int nTiles = ciSlice >> 5;

  __shared__ unsigned short sIn[10 * 18 * 40];

  int tid = threadIdx.x;
  int lane = tid & 63, wave = tid >> 6;
  int wc = wave >> 1, wp = wave & 1;
  int l15 = lane & 15, q = lane >> 4;

  for (int i = tid; i < (10 * 18 * 40) / 2; i += 256) ((unsigned int*)sIn)[i] = 0u;

  floatx4 acc[4][4];
#pragma unroll
  for (int ct = 0; ct < 4; ++ct)
#pragma unroll
    for (int pt = 0; pt < 4; ++pt) acc[ct][pt] = (floatx4){0.f, 0.f, 0.f, 0.f};

  int coBase = cb * 128 + wc * 64;
  int gr0 = ph * 7;
  int sr0 = 1 - ph;

  // per-thread staging slots: 18 elements, offsets hoisted out of the K-loop
  int gofs[18], lofs[18];
#pragma unroll
  for (int k = 0; k < 18; ++k) {
    int i = tid + k * 256;
    int px = i & 15, r9 = i >> 4;
    int rr = r9 % 9, ci = r9 / 9;
    gofs[k] = ci * 256 + (gr0 + rr) * 16 + px;
    lofs[k] = ((sr0 + rr) * 18 + 1 + px) * 40 + ci;
  }
  const float* inbF = (const float*)inv + (size_t)b * Cin * 256;
  const unsigned short* inbU = (const unsigned short*)inv + (size_t)b * Cin * 256;

  unsigned int pf[18];
  {
    int ci0 = slice * ciSlice;
    if (inBf16) {
#pragma unroll
      for (int k = 0; k < 18; ++k) pf[k] = inbU[(size_t)ci0 * 256 + gofs[k]];
    } else {
#pragma unroll
      for (int k = 0; k < 18; ++k)
        pf[k] = __float_as_uint(inbF[(size_t)ci0 * 256 + gofs[k]]);
    }
  }

  for (int ct2 = 0; ct2 < nTiles; ++ct2) {
    int ci0 = slice * ciSlice + ct2 * 32;
    __syncthreads();
    if (inBf16) {
#pragma unroll
      for (int k = 0; k < 18; ++k) sIn[lofs[k]] = (unsigned short)pf[k];
    } else {
#pragma unroll
      for (int k = 0; k < 18; ++k) sIn[lofs[k]] = f2bf(__uint_as_float(pf[k]));
    }
    __syncthreads();
    // prefetch next chunk while MFMAs below execute
    if (ct2 + 1 < nTiles) {
      int cin0 = ci0 + 32;
      if (inBf16) {
#pragma unroll
        for (int k = 0; k < 18; ++k) pf[k] = inbU[(size_t)cin0 * 256 + gofs[k]];
      } else {
#pragma unroll
        for (int k = 0; k < 18; ++k)
          pf[k] = __float_as_uint(inbF[(size_t)cin0 * 256 + gofs[k]]);
      }
    }
#pragma unroll
    for (int ky = 0; ky < 3; ++ky) {
#pragma unroll
      for (int kx = 0; kx < 3; ++kx) {
        int tap = ky * 3 + kx;
        const unsigned short* wbase =
            wT + ((size_t)(tap * Cout + coBase + l15)) * Cin + ci0 + q * 8;
        short8 af[4];
#pragma unroll
        for (int ct = 0; ct < 4; ++ct)
          af[ct] = *(const short8*)(wbase + (size_t)ct * 16 * Cin);
        short8 bf[4];
#pragma unroll
        for (int pt = 0; pt < 4; ++pt) {
          int sRow = wp * 4 + pt + ky;
          int sCol = l15 + kx;
          bf[pt] = *(const short8*)&sIn[(sRow * 18 + sCol) * 40 + q * 8];
        }
#pragma unroll
        for (int ct = 0; ct < 4; ++ct)
#pragma unroll
          for (int pt = 0; pt < 4; ++pt)
            acc[ct][pt] = __builtin_amdgcn_mfma_f32_16x16x32_bf16(
                af[ct], bf[pt], acc[ct][pt], 0, 0, 0);
      }
    }
  }

  float* po = part + ((size_t)(slice * B8 + b) * Cout) * 256;
#pragma unroll
  for (int ct = 0; ct < 4; ++ct) {
#pragma unroll
    for (int pt = 0; pt < 4; ++pt) {
      int co = coBase + ct * 16 + q * 4;
      int px = ph * 128 + wp * 64 + pt * 16 + l15;
#pragma unroll
      for (int r = 0; r < 4; ++r)
        po[(size_t)(co + r) * 256 + px] = acc[ct][pt][r];
    }
  }
}

// ---------------------------------------------------------------------------
// conv1 combine: sum 8 K-slices + BN + ReLU -> x2cat bf16, plus pooled-mean
// broadcast into channels [512,1024). grid.x = B8*512, block=256.
// ---------------------------------------------------------------------------
__global__ __launch_bounds__(256) void combine1(
    const float* __restrict__ part, const float* __restrict__ scale,
    const float* __restrict__ shift, unsigned short* __restrict__ out,
    int Cout, int nSlice, int outStride)
{
  int c = blockIdx.x % Cout, b = blockIdx.x / Cout;
  int tid = threadIdx.x;
  float s = 0.0f;
  for (int sl = 0; sl < nSlice; ++sl)
    s += part[(((size_t)sl * B8 + b) * Cout + c) * 256 + tid];
  float v = fmaf(s, scale[c], shift[c]);
  v = v > 0.0f ? v : 0.0f;
  out[((size_t)b * outStride + c) * 256 + tid] = f2bf(v);
  __shared__ float red[4];
  float w = v;
#pragma unroll
  for (int off = 32; off > 0; off >>= 1) w += __shfl_down(w, off, 64);
  if ((tid & 63) == 0) red[tid >> 6] = w;
  __syncthreads();
  float m = (red[0] + red[1] + red[2] + red[3]) * (1.0f / 256.0f);
  out[((size_t)b * outStride + Cout + c) * 256 + tid] = f2bf(m);
}

// ---------------------------------------------------------------------------
// conv2 combine: sum 4 K-slices + BN + ReLU -> x2T bf16 TRANSPOSED [b][px][ci]
// grid.x = 8b * 16pxg * 4cg ; block 256 = (c16 = tid>>4, px16 = tid&15).
// ---------------------------------------------------------------------------
__global__ __launch_bounds__(256) void combine2T(
    const float* __restrict__ part, const float* __restrict__ scale,
    const float* __restrict__ shift, unsigned short* __restrict__ x2T)
{
  int t = blockIdx.x;
  int cg = t & 3;
  int pxg = (t >> 2) & 15;
  int b = t >> 6;
  int c16 = threadIdx.x >> 4, px16 = threadIdx.x & 15;
  int px = pxg * 16 + px16;
#pragma unroll
  for (int k = 0; k < 4; ++k) {
    int cBase = cg * 256 + k * 64 + c16 * 4;
    unsigned short v4[4];
#pragma unroll
    for (int j = 0; j < 4; ++j) {
      int c = cBase + j;
      float s = 0.0f;
#pragma unroll
      for (int sl = 0; sl < 4; ++sl)
        s += part[(((size_t)sl * B8 + b) * 1024 + c) * 256 + px];
      float v = fmaf(s, scale[c], shift[c]);
      v4[j] = f2bf(v > 0.0f ? v : 0.0f);
    }
    *(ushort2*)&x2T[((size_t)b * 256 + px) * 1024 + cBase] =
        *(ushort2*)&v4[0];
    *(ushort2*)&x2T[((size_t)b * 256 + px) * 1024 + cBase + 2] =
        *(ushort2*)&v4[2];
  }
}

// ---------------------------------------------------------------------------
// cls1 1x1 (1024->4928) as register-only MFMA GEMM. Per batch:
// D[4928co x 256px] = W[4928x1024] * X^T. A & B frags straight from global
// (both 16B-contiguous along ci). grid.x = 77 coBlk * 8 b, block = 4 waves.
// ---------------------------------------------------------------------------
__global__ __launch_bounds__(256, 2) void hyper_gemm(
    const unsigned short* __restrict__ wH,  // [4928,1024] bf16
    const unsigned short* __restrict__ x2T, // [8,256,1024] bf16
    const float* __restrict__ bias,         // [4928]
    float* __restrict__ hyper)              // [8,4928,256] fp32
{
  int cb = blockIdx.x % 77, b = blockIdx.x / 77;
  int tid = threadIdx.x;
  int lane = tid & 63, w = tid >> 6;
  int l15 = lane & 15, q = lane >> 4;

  floatx4 acc[4][4];
#pragma unroll
  for (int ct = 0; ct < 4; ++ct)
#pragma unroll
    for (int pt = 0; pt < 4; ++pt) acc[ct][pt] = (floatx4){0.f, 0.f, 0.f, 0.f};

  const unsigned short* wp0 = wH + ((size_t)(cb * 64 + l15)) * 1024 + q * 8;
  const unsigned short* xp0 =
      x2T + ((size_t)(b * 256 + w * 64 + l15)) * 1024 + q * 8;

  for (int ci0 = 0; ci0 < 1024; ci0 += 32) {
    short8 af[4], bf[4];
#pragma unroll
    for (int ct = 0; ct < 4; ++ct)
      af[ct] = *(const short8*)(wp0 + (size_t)ct * 16 * 1024 + ci0);
#pragma unroll
    for (int pt = 0; pt < 4; ++pt)
      bf[pt] = *(const short8*)(xp0 + (size_t)pt * 16 * 1024 + ci0);
#pragma unroll
    for (int ct = 0; ct < 4; ++ct)
#pragma unroll
      for (int pt = 0; pt < 4; ++pt)
        acc[ct][pt] = __builtin_amdgcn_mfma_f32_16x16x32_bf16(
            af[ct], bf[pt], acc[ct][pt], 0, 0, 0);
  }

#pragma unroll
  for (int ct = 0; ct < 4; ++ct) {
    int co = cb * 64 + ct * 16 + q * 4;
#pragma unroll
    for (int pt = 0; pt < 4; ++pt) {
      int px = w * 64 + pt * 16 + l15;
#pragma unroll
      for (int r = 0; r < 4; ++r)
        hyper[((size_t)b * 4928 + co + r) * 256 + px] = acc[ct][pt][r] + bias[co + r];
    }
  }
}

// ---------------------------------------------------------------------------
// conv3x3 256->48 + BN + ReLU on 128x128 via bf16 MFMA.
// Block = one 16x16 spatial tile, all 48 couts. 4 waves x 4 rows each.
// LDS: 18x18 halo x 32ci (pixel-major, ciPad 40). grid.x = 8b * 64 tiles.
// Software-pipelined: next chunk's loads (32 scalars/thread, stride-64KB)
// held in regs across the compute phase.
// ---------------------------------------------------------------------------
__global__ __launch_bounds__(256, 2) void conv3x3_hi_mfma(
    const float* __restrict__ in,          // [B8,256,128,128]
    const unsigned short* __restrict__ wT, // [9,48,256] bf16
    const float* __restrict__ scale, const float* __restrict__ shift,
    float* __restrict__ out)               // [B8,48,128,128]
{
  int t = blockIdx.x;
  int tile = t & 63;
  int b = t >> 6;
  int ty0 = (tile >> 3) << 4, tx0 = (tile & 7) << 4;

  __shared__ unsigned short sIn[18 * 18 * 40];

  int tid = threadIdx.x;
  int lane = tid & 63, w = tid >> 6;
  int l15 = lane & 15, q = lane >> 4;

  // slot precompute (2 slots/thread max; 324 halo slots)
  int slotA = tid;
  int rowA = slotA / 18, colA = slotA % 18;
  int gyA = ty0 + rowA - 1, gxA = tx0 + colA - 1;
  bool vA = (unsigned)gyA < 128u && (unsigned)gxA < 128u;
  const float* gA = in + (size_t)b * 256 * 16384 + (vA ? (gyA * 128 + gxA) : 0);
  int slotB = 256 + tid;
  bool hasB = tid < 68;
  int rowB = slotB / 18, colB = slotB % 18;
  int gyB = ty0 + rowB - 1, gxB = tx0 + colB - 1;
  bool vB = hasB && (unsigned)gyB < 128u && (unsigned)gxB < 128u;
  const float* gB = in + (size_t)b * 256 * 16384 + (vB ? (gyB * 128 + gxB) : 0);

  floatx4 acc[3][4];
#pragma unroll
  for (int ct = 0; ct < 3; ++ct)
#pragma unroll
    for (int pt = 0; pt < 4; ++pt) acc[ct][pt] = (floatx4){0.f, 0.f, 0.f, 0.f};

  float pA[32], pB[32];
#pragma unroll
  for (int cp = 0; cp < 32; ++cp) pA[cp] = vA ? gA[(size_t)cp * 16384] : 0.0f;
  if (hasB) {
#pragma unroll
    for (int cp = 0; cp < 32; ++cp) pB[cp] = vB ? gB[(size_t)cp * 16384] : 0.0f;
  }

  for (int ci0 = 0; ci0 < 256; ci0 += 32) {
    __syncthreads();
    unsigned int* sU = (unsigned int*)sIn;
#pragma unroll
    for (int cp = 0; cp < 16; ++cp)
      sU[slotA * 20 + cp] =
          (unsigned)f2bf(pA[2 * cp]) | ((unsigned)f2bf(pA[2 * cp + 1]) << 16);
    if (hasB) {
#pragma unroll
      for (int cp = 0; cp < 16; ++cp)
        sU[slotB * 20 + cp] =
            (unsigned)f2bf(pB[2 * cp]) | ((unsigned)f2bf(pB[2 * cp + 1]) << 16);
    }
    __syncthreads();
    // prefetch next chunk; overlaps the 108 MFMAs below
    if (ci0 + 32 < 256) {
#pragma unroll
      for (int cp = 0; cp < 32; ++cp)
        pA[cp] = vA ? gA[(size_t)(ci0 + 32 + cp) * 16384] : 0.0f;
      if (hasB) {
#pragma unroll
        for (int cp = 0; cp < 32; ++cp)
          pB[cp] = vB ? gB[(size_t)(ci0 + 32 + cp) * 16384] : 0.0f;
      }
    }
#pragma unroll
    for (int ky = 0; ky < 3; ++ky) {
#pragma unroll
      for (int kx = 0; kx < 3; ++kx) {
        int tap = ky * 3 + kx;
        const unsigned short* wbase =
            wT + ((size_t)(tap * 48 + l15)) * 256 + ci0 + q * 8;
        short8 af[3];
#pragma unroll
        for (int ct = 0; ct < 3; ++ct)
          af[ct] = *(const short8*)(wbase + (size_t)ct * 16 * 256);
        short8 bf[4];
#pragma unroll
        for (int pt = 0; pt < 4; ++pt) {
          int sRow = w * 4 + pt + ky;
          int sCol = l15 + kx;
          bf[pt] = *(const short8*)&sIn[(sRow * 18 + sCol) * 40 + q * 8];
        }
#pragma unroll
        for (int ct = 0; ct < 3; ++ct)
#pragma unroll
          for (int pt = 0; pt < 4; ++pt)
            acc[ct][pt] = __builtin_amdgcn_mfma_f32_16x16x32_bf16(
                af[ct], bf[pt], acc[ct][pt], 0, 0, 0);
      }
    }
  }

#pragma unroll
  for (int ct = 0; ct < 3; ++ct) {
#pragma unroll
    for (int pt = 0; pt < 4; ++pt) {
      int oy = ty0 + w * 4 + pt, ox = tx0 + l15;
#pragma unroll
      for (int r = 0; r < 4; ++r) {
        int c = ct * 16 + q * 4 + r;
        float v = fmaf(acc[ct][pt][r], scale[c], shift[c]);
        v = v > 0.0f ? v : 0.0f;
        out[((size_t)b * 48 + c) * 16384 + oy * 128 + ox] = v;
      }
    }
  }
}

// ---------------------------------------------------------------------------
__global__ __launch_bounds__(256) void conv1x1_lo(
    const float* __restrict__ in, const float* __restrict__ wgt,
    const float* __restrict__ bias, float* __restrict__ out)
{
  int b = blockIdx.x >> 6;
  int px = ((blockIdx.x & 63) << 8) + threadIdx.x;
  float acc[16];
#pragma unroll
  for (int co = 0; co < 16; ++co) acc[co] = 0.0f;
#pragma unroll 4
  for (int ci = 0; ci < 48; ++ci) {
    float xv = in[((size_t)b * 48 + ci) * 16384 + px];
#pragma unroll
    for (int co = 0; co < 16; ++co) acc[co] = fmaf(xv, wgt[co * 48 + ci], acc[co]);
  }
#pragma unroll
  for (int co = 0; co < 16; ++co)
    out[((size_t)b * 16 + co) * 16384 + px] = acc[co] + bias[co];
}

// ---------------------------------------------------------------------------
// dynamic per-pixel MLP: 18 -> 16 -> 16 -> 256 (see round-0 comments).
// ---------------------------------------------------------------------------
__global__ __launch_bounds__(256) void dyn_mlp(
    const float* __restrict__ hyper, const float* __restrict__ c1,
    const float* __restrict__ catS, const float* __restrict__ catB,
    float* __restrict__ out)
{
  int t = blockIdx.x;
  int q = t & 3;
  int h = (t >> 2) & 15;
  int b = t >> 6;
  int tid = threadIdx.x;
  int xf = tid & 127, r2 = tid >> 7;
  int w = xf >> 3;

  __shared__ float smem[16 * 578];
  __shared__ float sB2[16 * 33];

  const float* hypb = hyper + (size_t)b * 4928 * 256 + h * 16;

  for (int i = tid; i < 576 * 16; i += 256) {
    int ch = i >> 4, ww = i & 15;
    smem[ww * 578 + ch] = hypb[(size_t)ch * 256 + ww];
  }

  float cs[18], cb[18];
#pragma unroll
  for (int i = 0; i < 18; ++i) { cs[i] = catS[i]; cb[i] = catB[i]; }

  float inpv[4][18];
  int yf0 = h * 8 + r2 * 4;
  float cx = (float)(xf & 7) * 0.125f;
#pragma unroll
  for (int k = 0; k < 4; ++k) {
    inpv[k][0] = fmaf(cx, cs[0], cb[0]);
    inpv[k][1] = fmaf((float)((yf0 + k) & 7) * 0.125f, cs[1], cb[1]);
#pragma unroll
    for (int ci = 0; ci < 16; ++ci) {
      float v = c1[((size_t)b * 16 + ci) * 16384 + (size_t)(yf0 + k) * 128 + xf];
      inpv[k][2 + ci] = fmaf(v, cs[2 + ci], cb[2 + ci]);
    }
  }
  __syncthreads();

  const float* sw = smem + w * 578;
  float h0v[4][16];
  {
    const float2* w0p = (const float2*)sw;
#pragma unroll
    for (int co = 0; co < 16; ++co) {
      float a0 = sw[288 + co], a1 = a0, a2 = a0, a3 = a0;
#pragma unroll
      for (int c2 = 0; c2 < 9; ++c2) {
        float2 wv = w0p[co * 9 + c2];
        a0 = fmaf(wv.x, inpv[0][2 * c2], a0); a0 = fmaf(wv.y, inpv[0][2 * c2 + 1], a0);
        a1 = fmaf(wv.x, inpv[1][2 * c2], a1); a1 = fmaf(wv.y, inpv[1][2 * c2 + 1], a1);
        a2 = fmaf(wv.x, inpv[2][2 * c2], a2); a2 = fmaf(wv.y, inpv[2][2 * c2 + 1], a2);
        a3 = fmaf(wv.x, inpv[3][2 * c2], a3); a3 = fmaf(wv.y, inpv[3][2 * c2 + 1], a3);
      }
      h0v[0][co] = fmaxf(a0, 0.0f); h0v[1][co] = fmaxf(a1, 0.0f);
      h0v[2][co] = fmaxf(a2, 0.0f); h0v[3][co] = fmaxf(a3, 0.0f);
    }
  }
  float h1v[4][16];
  {
    const float2* w1p = (const float2*)(sw + 304);
#pragma unroll
    for (int co = 0; co < 16; ++co) {
      float a0 = sw[560 + co], a1 = a0, a2 = a0, a3 = a0;
#pragma unroll
      for (int c2 = 0; c2 < 8; ++c2) {
        float2 wv = w1p[co * 8 + c2];
        a0 = fmaf(wv.x, h0v[0][2 * c2], a0); a0 = fmaf(wv.y, h0v[0][2 * c2 + 1], a0);
        a1 = fmaf(wv.x, h0v[1][2 * c2], a1); a1 = fmaf(wv.y, h0v[1][2 * c2 + 1], a1);
        a2 = fmaf(wv.x, h0v[2][2 * c2], a2); a2 = fmaf(wv.y, h0v[2][2 * c2 + 1], a2);
        a3 = fmaf(wv.x, h0v[3][2 * c2], a3); a3 = fmaf(wv.y, h0v[3][2 * c2 + 1], a3);
      }
      h1v[0][co] = fmaxf(a0, 0.0f); h1v[1][co] = fmaxf(a1, 0.0f);
      h1v[2][co] = fmaxf(a2, 0.0f); h1v[3][co] = fmaxf(a3, 0.0f);
    }
  }

  for (int chunk = 0; chunk < 2; ++chunk) {
    int po0 = q * 64 + chunk * 32;
    __syncthreads();
    for (int i = tid; i < 8192; i += 256) {
      int ch = i >> 4, ww = i & 15;
      smem[ww * 518 + ch] = hypb[(size_t)(576 + po0 * 16 + ch) * 256 + ww];
    }
    for (int i = tid; i < 512; i += 256) {
      int po = i >> 4, ww = i & 15;
      sB2[ww * 33 + po] = hypb[(size_t)(4672 + po0 + po) * 256 + ww];
    }
    __syncthreads();
    const float2* w2p = (const float2*)(smem + w * 518);
    const float* sb2 = sB2 + w * 33;
#pragma unroll 4
    for (int po = 0; po < 32; ++po) {
      float a0 = sb2[po], a1 = a0, a2 = a0, a3 = a0;
#pragma unroll
      for (int c2 = 0; c2 < 8; ++c2) {
        float2 wv = w2p[po * 8 + c2];
        a0 = fmaf(wv.x, h1v[0][2 * c2], a0); a0 = fmaf(wv.y, h1v[0][2 * c2 + 1], a0);
        a1 = fmaf(wv.x, h1v[1][2 * c2], a1); a1 = fmaf(wv.y, h1v[1][2 * c2 + 1], a1);
        a2 = fmaf(wv.x, h1v[2][2 * c2], a2); a2 = fmaf(wv.y, h1v[2][2 * c2 + 1], a2);
        a3 = fmaf(wv.x, h1v[3][2 * c2], a3); a3 = fmaf(wv.y, h1v[3][2 * c2 + 1], a3);
      }
      size_t ob = ((size_t)b * 256 + po0 + po) * 16384 + (size_t)yf0 * 128 + xf;
      out[ob] = a0; out[ob + 128] = a1; out[ob + 256] = a2; out[ob + 384] = a3;
    }
  }
}

// ---------------------------------------------------------------------------
extern "C" void kernel_launch(void* const* d_in, const int* in_sizes, int n_in,
                              void* d_out, int out_size, void* d_ws, size_t ws_size,
                              hipStream_t stream) {
  const float* res5 = (const float*)d_in[0];
  const float* res2 = (const float*)d_in[1];
  const float* bw   = (const float*)d_in[2];
  const float* bn1s = (const float*)d_in[3];
  const float* bn1b = (const float*)d_in[4];
  const float* c0w  = (const float*)d_in[5];
  const float* bn2s = (const float*)d_in[6];
  const float* bn2b = (const float*)d_in[7];
  const float* cls1w = (const float*)d_in[8];
  const float* cls1b = (const float*)d_in[9];
  const float* c1aw = (const float*)d_in[10];
  const float* bn3s = (const float*)d_in[11];
  const float* bn3b = (const float*)d_in[12];
  const float* c1bw = (const float*)d_in[13];
  const float* c1bb = (const float*)d_in[14];
  const float* catS = (const float*)d_in[15];
  const float* catB = (const float*)d_in[16];
  float* out = (float*)d_out;
  float* ws = (float*)d_ws;

  // ws layout (float offsets), lifetime-aliased, peak 25,296,896 fl = 101.2 MB
  unsigned short* wT2u  = (unsigned short*)(ws);             // [0, 4718592)
  unsigned short* x2cat = (unsigned short*)(ws + 4718592);   // 2,097,152 us
  unsigned short* wT48  = (unsigned short*)(ws + 4718592);   // alias (after conv2)
  unsigned short* x2T   = (unsigned short*)(ws + 5767168);   // 2,097,152 us
  float* hyper          = ws + 6815744;                      // 10,092,544 fl
  unsigned short* wT1u  = (unsigned short*)(ws + 6815744);   // alias (dead pre-hyper)
  float* partial        = ws + 16908288;                     // 8,388,608 fl
  unsigned short* wH    = (unsigned short*)(ws + 16908288);  // alias (after combine2T)
  float* c1mid          = ws + 16908288;                     // alias (after hyper_gemm)
  float* c1             = ws + 23199744;                     // 2,097,152 fl

  // conv weights -> bf16 tap-major
  wtransform<<<(512 * 2048 + 255) / 256, 256, 0, stream>>>(bw, wT1u, 512, 2048);
  wtransform<<<(1024 * 1024 + 255) / 256, 256, 0, stream>>>(c0w, wT2u, 1024, 1024);

  // bottleneck conv (2048->512), 8 K-slices
  conv3x3_mfma<<<8 * 4 * 2 * 8, 256, 0, stream>>>(res5, wT1u, partial, 2048, 512, 4, 8, 0);
  combine1<<<8 * 512, 256, 0, stream>>>(partial, bn1s, bn1b, x2cat, 512, 8, 1024);
  // cls0 conv (1024->1024), 4 K-slices, bf16 input
  conv3x3_mfma<<<8 * 8 * 2 * 4, 256, 0, stream>>>(x2cat, wT2u, partial, 1024, 1024, 8, 4, 1);
  combine2T<<<8 * 16 * 4, 256, 0, stream>>>(partial, bn2s, bn2b, x2T);
  // cls1 1x1 (1024->4928) MFMA  (wH aliases dead partial)
  cvt_bf16<<<(4928 * 1024 + 255) / 256, 256, 0, stream>>>(cls1w, wH, 4928 * 1024);
  hyper_gemm<<<77 * 8, 256, 0, stream>>>(wH, x2T, cls1b, hyper);
  // low-level branch (wT48 aliases dead x2cat; c1mid aliases dead wH/partial)
  wtransform<<<(48 * 256 + 255) / 256, 256, 0, stream>>>(c1aw, wT48, 48, 256);
  conv3x3_hi_mfma<<<8 * 64, 256, 0, stream>>>(res2, wT48, bn3s, bn3b, c1mid);
  conv1x1_lo<<<8 * 64, 256, 0, stream>>>(c1mid, c1bw, c1bb, c1);
  // dynamic MLP
  dyn_mlp<<<8 * 16 * 4, 256, 0, stream>>>(hyper, c1, catS, catB, out);
}